// Round 4
// baseline (1048.104 us; speedup 1.0000x reference)
//
#include <hip/hip_runtime.h>

#define Bn 4096
#define Tn 100
#define Dn 64
#define Hn 128

typedef _Float16 half8v __attribute__((ext_vector_type(8)));
typedef _Float16 half4v __attribute__((ext_vector_type(4)));
typedef float    float4v __attribute__((ext_vector_type(4)));
typedef float    float2v __attribute__((ext_vector_type(2)));
typedef long     long2v  __attribute__((ext_vector_type(2)));

__device__ __forceinline__ float fast_tanh(float x) {
    float e = __expf(x + x);
    return 1.0f - 2.0f * __builtin_amdgcn_rcpf(e + 1.0f);
}
__device__ __forceinline__ float fast_sig(float x) {
    return __builtin_amdgcn_rcpf(1.0f + __expf(-x));
}
__device__ __forceinline__ float4v tanh4(float4v u) {
    float4v a;
#pragma unroll
    for (int r = 0; r < 4; r++) a[r] = fast_tanh(u[r]);
    return a;
}
__device__ __forceinline__ half4v pack4(float4v v) {
    half4v p;
#pragma unroll
    for (int r = 0; r < 4; r++) p[r] = (_Float16)v[r];
    return p;
}
__device__ __forceinline__ int pack_fp8x4(float a, float b, float c, float d) {
    int v = __builtin_amdgcn_cvt_pk_fp8_f32(a, b, 0, false);
    v = __builtin_amdgcn_cvt_pk_fp8_f32(c, d, v, true);
    return v;
}
__device__ __forceinline__ long pack_fp8x8s(float4v a, float4v b, float s) {
    int lo = pack_fp8x4(a[0]*s, a[1]*s, a[2]*s, a[3]*s);
    int hi = pack_fp8x4(b[0]*s, b[1]*s, b[2]*s, b[3]*s);
    return (long)(((unsigned long long)(unsigned)hi << 32) | (unsigned)lo);
}

// fp16 A-operand fragment of stationary weight W [n x ld]: lane gets W[n][k..k+7].
__device__ __forceinline__ half8v load_wfrag(const float* __restrict__ W, int ld, int n, int k) {
    const float* p = W + (size_t)n * ld + k;
    float4v a = *(const float4v*)p;
    float4v b = *(const float4v*)(p + 4);
    half8v r;
    r[0] = (_Float16)a[0]; r[1] = (_Float16)a[1]; r[2] = (_Float16)a[2]; r[3] = (_Float16)a[3];
    r[4] = (_Float16)b[0]; r[5] = (_Float16)b[1]; r[6] = (_Float16)b[2]; r[7] = (_Float16)b[3];
    return r;
}

// Persistent ODE-RNN. 256 blocks x 512 threads (8 waves, 2/SIMD).
// 18 barrier intervals/step: [loop-top: u_h + gi + gh_old] + 16 RK exchanges (fp8)
// + [Abar: h-update + gh-update via M2=Whh*W2 + GRU].
// fp8 exchange layout (row stride 144B): pos(k)=64*(k>>6)+16*(((k>>3))&3... writer
// uses ppos formula; reader: 2x ds_read_b128 per gemm.
__global__ __launch_bounds__(512, 2) void odernn_kernel(
    const float* __restrict__ x_seq, const float* __restrict__ t_seq,
    const float* __restrict__ W1,   const float* __restrict__ b1,
    const float* __restrict__ W2,   const float* __restrict__ b2,
    const float* __restrict__ W_ih, const float* __restrict__ W_hh,
    const float* __restrict__ b_ih, const float* __restrict__ b_hh,
    const float* __restrict__ W_mu, const float* __restrict__ b_mu,
    const float* __restrict__ W_lv, const float* __restrict__ b_lv,
    float* __restrict__ out)
{
    __shared__ _Float16 vbuf[16 * 136];                                  // h (fp16)
    __shared__ __attribute__((aligned(16))) unsigned char abuf8[2][16 * 144];  // a_i / A / Abar (fp8)
    __shared__ _Float16 xbuf[16 * 72];
    __shared__ float    ts_l[Tn];
    __shared__ float    c1s[Hn];          // b2 @ W1^T
    __shared__ float    c2s[3 * Hn];      // Whh @ b2

    const int tid  = threadIdx.x;
    const int lane = tid & 63;
    const int w    = tid >> 6;
    const int q    = lane >> 4;
    const int m    = lane & 15;
    const int blk  = blockIdx.x;

    if (tid < Tn) ts_l[tid] = t_seq[tid];
    for (int i = tid; i < 16 * 136; i += 512) vbuf[i] = (_Float16)0.f;   // h0 = 0
    if (tid < Hn) {
        float acc = 0.f;
        const float* r1 = W1 + (size_t)tid * Hn;
#pragma unroll 4
        for (int j = 0; j < Hn; j++) acc += b2[j] * r1[j];
        c1s[tid] = acc;
    } else {
        int i = tid - Hn;                 // 0..383
        float acc = 0.f;
        const float* rh = W_hh + (size_t)i * Hn;
#pragma unroll 4
        for (int j = 0; j < Hn; j++) acc += rh[j] * b2[j];
        c2s[i] = acc;
    }

    // ---- fp16 stationary fragments ----
    const int n0 = 16 * w + m;
    half8v w1f[4], whhf[3][4], wihf[3][2];
#pragma unroll
    for (int kt = 0; kt < 4; kt++) w1f[kt] = load_wfrag(W1, Hn, n0, 32 * kt + q * 8);
#pragma unroll
    for (int g = 0; g < 3; g++) {
        int n = 128 * g + n0;
#pragma unroll
        for (int kt = 0; kt < 4; kt++) whhf[g][kt] = load_wfrag(W_hh, Hn, n, 32 * kt + q * 8);
#pragma unroll
        for (int kt = 0; kt < 2; kt++) wihf[g][kt] = load_wfrag(W_ih, Dn, n, 32 * kt + q * 8);
    }
    float4v b1q = *(const float4v*)(b1 + 16 * w + q * 4);
    float4v b2q = *(const float4v*)(b2 + 16 * w + q * 4);
    float4v bihq[3], bhhq[3];
#pragma unroll
    for (int g = 0; g < 3; g++) {
        bihq[g] = *(const float4v*)(b_ih + 128 * g + 16 * w + q * 4);
        bhhq[g] = *(const float4v*)(b_hh + 128 * g + 16 * w + q * 4);
    }

    // ---- fused precompute: M = W1@W2 and M2[g] = Whh_g@W2 (A-layout frags) ----
    float4v aM[4][2], aG[3][4][2];
#pragma unroll
    for (int kt = 0; kt < 4; kt++) {
        float4v zz = {0.f, 0.f, 0.f, 0.f};
        aM[kt][0] = zz; aM[kt][1] = zz;
#pragma unroll
        for (int g = 0; g < 3; g++) { aG[g][kt][0] = zz; aG[g][kt][1] = zz; }
    }
    {
        const float* w1row = W1   + (size_t)n0 * Hn;
        const float* h0row = W_hh + (size_t)n0 * Hn;
        const float* h1row = W_hh + (size_t)(128 + n0) * Hn;
        const float* h2row = W_hh + (size_t)(256 + n0) * Hn;
        for (int j = 0; j < Hn; j++) {
            float s0 = w1row[j], s1 = h0row[j], s2 = h1row[j], s3 = h2row[j];
            const float* w2r = W2 + (size_t)j * Hn + q * 8;
#pragma unroll
            for (int kt = 0; kt < 4; kt++) {
                float4v aa = *(const float4v*)(w2r + 32 * kt);
                float4v bb = *(const float4v*)(w2r + 32 * kt + 4);
                aM[kt][0] += s0 * aa;      aM[kt][1] += s0 * bb;
                aG[0][kt][0] += s1 * aa;   aG[0][kt][1] += s1 * bb;
                aG[1][kt][0] += s2 * aa;   aG[1][kt][1] += s2 * bb;
                aG[2][kt][0] += s3 * aa;   aG[2][kt][1] += s3 * bb;
            }
        }
    }
    long w21f8[4], m2f8[3][4], w2f8[4];
#pragma unroll
    for (int kt = 0; kt < 4; kt++) {
        w21f8[kt] = pack_fp8x8s(aM[kt][0], aM[kt][1], 64.0f);
#pragma unroll
        for (int g = 0; g < 3; g++) m2f8[g][kt] = pack_fp8x8s(aG[g][kt][0], aG[g][kt][1], 64.0f);
        const float* p = W2 + (size_t)n0 * Hn + 32 * kt + q * 8;
        w2f8[kt] = pack_fp8x8s(*(const float4v*)p, *(const float4v*)(p + 4), 64.0f);
    }

    float4v h = {0.f, 0.f, 0.f, 0.f};

    const int xrow = tid >> 5;
    const int xcol = (tid & 31) * 2;
    const float* xptr = x_seq + (size_t)(blk * 16 + xrow) * (Tn * Dn) + xcol;
    float2v xreg = *(const float2v*)xptr;

    const int wslot = m * 136 + 16 * w + q * 4;                 // vbuf C-layout slot
    // fp8 writer position: n = 16w+4q+r  ->  permuted k position (4B aligned)
    const int ppos = 64 * (w >> 2) + 16 * ((2 * (w & 3) + (q >> 1)) & 3)
                   + 8 * ((w >> 1) & 1) + 4 * (q & 1);
    const float4v zero4 = {0.f, 0.f, 0.f, 0.f};

    auto store_a = [&](int pp, float4v v) {
        *(int*)(abuf8[pp] + m * 144 + ppos) = pack_fp8x4(v[0], v[1], v[2], v[3]);
    };
    // fp8 gemm over K=128: 2x ds_read_b128, 4 MFMAs in 2 chains
    auto gemm8 = [&](const long* Wf, int pp) -> float4v {
        const unsigned char* p = abuf8[pp] + m * 144;
        long2v L0 = *(const long2v*)(p + q * 16);
        long2v L1 = *(const long2v*)(p + 64 + q * 16);
        float4v o1 = zero4, o2 = zero4;
        o1 = __builtin_amdgcn_mfma_f32_16x16x32_fp8_fp8(Wf[0], L0[0], o1, 0, 0, 0);
        o2 = __builtin_amdgcn_mfma_f32_16x16x32_fp8_fp8(Wf[2], L1[0], o2, 0, 0, 0);
        o1 = __builtin_amdgcn_mfma_f32_16x16x32_fp8_fp8(Wf[1], L0[1], o1, 0, 0, 0);
        o2 = __builtin_amdgcn_mfma_f32_16x16x32_fp8_fp8(Wf[3], L1[1], o2, 0, 0, 0);
        return o1 + o2;
    };

    float4v c1q, c2q[3];
    __syncthreads();     // publish ts_l, c1s, c2s, vbuf(h0)
#pragma unroll
    for (int r = 0; r < 4; r++) c1q[r] = c1s[16 * w + q * 4 + r];
#pragma unroll
    for (int g = 0; g < 3; g++)
#pragma unroll
        for (int r = 0; r < 4; r++) c2q[g][r] = c2s[128 * g + 16 * w + q * 4 + r];

#pragma unroll 1
    for (int t = 0; t < Tn; ++t) {
        {
            _Float16* xp = xbuf + xrow * 72 + xcol;
            xp[0] = (_Float16)xreg[0]; xp[1] = (_Float16)xreg[1];
        }
        float tc   = ts_l[t];
        float tp   = (t > 0) ? ts_l[t - 1] : tc;
        float sub  = (tc - tp) * 0.25f;
        float hs   = 0.5f * sub;
        float s6   = sub * (1.0f / 6.0f);
        float hs64 = hs * (1.0f / 64.0f);
        float sb64 = sub * (1.0f / 64.0f);
        float s664 = s6 * (1.0f / 64.0f);
        __syncthreads();                  // publish xbuf + vbuf(h)
        if (t + 1 < Tn) xreg = *(const float2v*)(xptr + (t + 1) * Dn);

        // ---- loop-top interval: gi, u_h, gh_old (shared vbuf reads) ----
        float4v gi[3], gh[3], u_h;
        {
            const _Float16* xp = xbuf + m * 72 + q * 8;
            half8v xf0 = *(const half8v*)(xp);
            half8v xf1 = *(const half8v*)(xp + 32);
#pragma unroll
            for (int g = 0; g < 3; g++) {
                float4v acc = bihq[g];
                acc = __builtin_amdgcn_mfma_f32_16x16x32_f16(wihf[g][0], xf0, acc, 0, 0, 0);
                acc = __builtin_amdgcn_mfma_f32_16x16x32_f16(wihf[g][1], xf1, acc, 0, 0, 0);
                gi[g] = acc;
            }
            const _Float16* vp = vbuf + m * 136 + q * 8;
            half8v bf0 = *(const half8v*)(vp);
            half8v bf1 = *(const half8v*)(vp + 32);
            half8v bf2 = *(const half8v*)(vp + 64);
            half8v bf3 = *(const half8v*)(vp + 96);
            float4v o1 = b1q, o2 = zero4;
            o1 = __builtin_amdgcn_mfma_f32_16x16x32_f16(w1f[0], bf0, o1, 0, 0, 0);
            o2 = __builtin_amdgcn_mfma_f32_16x16x32_f16(w1f[2], bf2, o2, 0, 0, 0);
            o1 = __builtin_amdgcn_mfma_f32_16x16x32_f16(w1f[1], bf1, o1, 0, 0, 0);
            o2 = __builtin_amdgcn_mfma_f32_16x16x32_f16(w1f[3], bf3, o2, 0, 0, 0);
            u_h = o1 + o2;
#pragma unroll
            for (int g = 0; g < 3; g++) {
                float4v acc = bhhq[g];
                acc = __builtin_amdgcn_mfma_f32_16x16x32_f16(whhf[g][0], bf0, acc, 0, 0, 0);
                acc = __builtin_amdgcn_mfma_f32_16x16x32_f16(whhf[g][1], bf1, acc, 0, 0, 0);
                acc = __builtin_amdgcn_mfma_f32_16x16x32_f16(whhf[g][2], bf2, acc, 0, 0, 0);
                acc = __builtin_amdgcn_mfma_f32_16x16x32_f16(whhf[g][3], bf3, acc, 0, 0, 0);
                gh[g] = acc;               // gh_old; updated after RK
            }
        }

        if (sub != 0.0f) {
            float4v Abar = zero4;
#pragma unroll 1
            for (int s = 0; s < 4; s++) {
                float4v a1 = tanh4(u_h);
                float4v A = a1;
                store_a(0, a1);
                __syncthreads();
                float4v g = gemm8(w21f8, 0);
                float4v u = u_h + hs64 * g + hs * c1q;
                float4v a2 = tanh4(u);
                A += 2.0f * a2;
                store_a(1, a2);
                __syncthreads();
                g = gemm8(w21f8, 1);
                u = u_h + hs64 * g + hs * c1q;
                float4v a3 = tanh4(u);
                A += 2.0f * a3;
                store_a(0, a3);
                __syncthreads();
                g = gemm8(w21f8, 0);
                u = u_h + sb64 * g + sub * c1q;
                float4v a4 = tanh4(u);
                A += a4;
                store_a(1, A);            // |A| <= 6
                __syncthreads();
                g = gemm8(w21f8, 1);
                u_h += s664 * g + sub * c1q;
                Abar += A;
            }
            // ---- final interval: Abar exchange -> h-update, gh-update ----
            store_a(0, Abar);             // |Abar| <= 24
            __syncthreads();
            {
                const unsigned char* p = abuf8[0] + m * 144;
                long2v L0 = *(const long2v*)(p + q * 16);
                long2v L1 = *(const long2v*)(p + 64 + q * 16);
                float4v o1 = zero4, o2 = zero4;
                o1 = __builtin_amdgcn_mfma_f32_16x16x32_fp8_fp8(w2f8[0], L0[0], o1, 0, 0, 0);
                o2 = __builtin_amdgcn_mfma_f32_16x16x32_fp8_fp8(w2f8[2], L1[0], o2, 0, 0, 0);
                o1 = __builtin_amdgcn_mfma_f32_16x16x32_fp8_fp8(w2f8[1], L0[1], o1, 0, 0, 0);
                o2 = __builtin_amdgcn_mfma_f32_16x16x32_fp8_fp8(w2f8[3], L1[1], o2, 0, 0, 0);
                float4v hd = o1 + o2;
                float fs = 4.0f * sub;
                h += s664 * hd + fs * b2q;
#pragma unroll
                for (int g = 0; g < 3; g++) {
                    float4v p1 = zero4, p2 = zero4;
                    p1 = __builtin_amdgcn_mfma_f32_16x16x32_fp8_fp8(m2f8[g][0], L0[0], p1, 0, 0, 0);
                    p2 = __builtin_amdgcn_mfma_f32_16x16x32_fp8_fp8(m2f8[g][2], L1[0], p2, 0, 0, 0);
                    p1 = __builtin_amdgcn_mfma_f32_16x16x32_fp8_fp8(m2f8[g][1], L0[1], p1, 0, 0, 0);
                    p2 = __builtin_amdgcn_mfma_f32_16x16x32_fp8_fp8(m2f8[g][3], L1[1], p2, 0, 0, 0);
                    gh[g] += s664 * (p1 + p2) + fs * c2q[g];
                }
            }
        }

        // ---- GRU (registers) + publish h ----
        {
            half4v pk;
#pragma unroll
            for (int r = 0; r < 4; r++) {
                float rr = fast_sig(gi[0][r] + gh[0][r]);
                float zz = fast_sig(gi[1][r] + gh[1][r]);
                float nn = fast_tanh(gi[2][r] + rr * gh[2][r]);
                float hv = (1.0f - zz) * nn + zz * h[r];
                h[r] = hv;
                pk[r] = (_Float16)hv;
            }
            *(half4v*)(vbuf + wslot) = pk;
        }
        // loop-top barrier publishes vbuf
    }

    __syncthreads();

    // ---- epilogue: mu / logvar ----
#pragma unroll
    for (int mat = 0; mat < 2; mat++) {
        const float* Wm = mat ? W_lv : W_mu;
        const float* bm = mat ? b_lv : b_mu;
        float4v acc = *(const float4v*)(bm + 16 * w + q * 4);
        const _Float16* p = vbuf + m * 136 + q * 8;
#pragma unroll
        for (int kt = 0; kt < 4; kt++) {
            half8v af = load_wfrag(Wm, Hn, n0, 32 * kt + q * 8);
            acc = __builtin_amdgcn_mfma_f32_16x16x32_f16(af, *(const half8v*)(p + kt * 32), acc, 0, 0, 0);
        }
        *(float4v*)(out + (size_t)mat * Bn * Hn + (size_t)(blk * 16 + m) * Hn + 16 * w + q * 4) = acc;
    }
}

extern "C" void kernel_launch(void* const* d_in, const int* in_sizes, int n_in,
                              void* d_out, int out_size, void* d_ws, size_t ws_size,
                              hipStream_t stream) {
    (void)in_sizes; (void)n_in; (void)d_ws; (void)ws_size; (void)out_size;
    odernn_kernel<<<dim3(Bn / 16), dim3(512), 0, stream>>>(
        (const float*)d_in[0],  (const float*)d_in[1],  (const float*)d_in[2],
        (const float*)d_in[3],  (const float*)d_in[4],  (const float*)d_in[5],
        (const float*)d_in[6],  (const float*)d_in[7],  (const float*)d_in[8],
        (const float*)d_in[9],  (const float*)d_in[10], (const float*)d_in[11],
        (const float*)d_in[12], (const float*)d_in[13], (float*)d_out);
}

// Round 5
// 883.572 us; speedup vs baseline: 1.1862x; 1.1862x over previous
//
#include <hip/hip_runtime.h>

#define Bn 4096
#define Tn 100
#define Dn 64
#define Hn 128

typedef _Float16 half8v __attribute__((ext_vector_type(8)));
typedef _Float16 half4v __attribute__((ext_vector_type(4)));
typedef float    float4v __attribute__((ext_vector_type(4)));
typedef float    float2v __attribute__((ext_vector_type(2)));
typedef long     long2v  __attribute__((ext_vector_type(2)));

__device__ __forceinline__ float fast_tanh(float x) {
    float e = __expf(x + x);
    return 1.0f - 2.0f * __builtin_amdgcn_rcpf(e + 1.0f);
}
__device__ __forceinline__ float fast_sig(float x) {
    return __builtin_amdgcn_rcpf(1.0f + __expf(-x));
}
__device__ __forceinline__ float4v tanh4(float4v u) {
    float4v a;
#pragma unroll
    for (int r = 0; r < 4; r++) a[r] = fast_tanh(u[r]);
    return a;
}
__device__ __forceinline__ half4v pack4(float4v v) {
    half4v p;
#pragma unroll
    for (int r = 0; r < 4; r++) p[r] = (_Float16)v[r];
    return p;
}
__device__ __forceinline__ int pack_fp8x4(float a, float b, float c, float d) {
    int v = __builtin_amdgcn_cvt_pk_fp8_f32(a, b, 0, false);
    v = __builtin_amdgcn_cvt_pk_fp8_f32(c, d, v, true);
    return v;
}
__device__ __forceinline__ long pack_fp8x8s(float4v a, float4v b, float s) {
    int lo = pack_fp8x4(a[0]*s, a[1]*s, a[2]*s, a[3]*s);
    int hi = pack_fp8x4(b[0]*s, b[1]*s, b[2]*s, b[3]*s);
    return (long)(((unsigned long long)(unsigned)hi << 32) | (unsigned)lo);
}

// fp16 A-operand fragment of stationary weight W [n x ld]: lane gets W[n][k..k+7].
__device__ __forceinline__ half8v load_wfrag(const float* __restrict__ W, int ld, int n, int k) {
    const float* p = W + (size_t)n * ld + k;
    float4v a = *(const float4v*)p;
    float4v b = *(const float4v*)(p + 4);
    half8v r;
    r[0] = (_Float16)a[0]; r[1] = (_Float16)a[1]; r[2] = (_Float16)a[2]; r[3] = (_Float16)a[3];
    r[4] = (_Float16)b[0]; r[5] = (_Float16)b[1]; r[6] = (_Float16)b[2]; r[7] = (_Float16)b[3];
    return r;
}

// Persistent ODE-RNN. 256 blocks x 512 threads (8 waves, 2/SIMD).
// 19 barrier intervals/step:
//  [loop-top: gi + u_h (fp16)] + 15 fp8 RK exchanges (last substep's A-exchange
//  merged into Abar) + [Abar (fp8) -> h-update] + [publish h] + [gh (fp16) -> GRU].
// fp8 exchange uses permuted writer positions so reader's natural 2x ds_read_b128
// yields correct fragments (validated R4: phys(k)=64*(kt>>1)+16*qk+8*(kt&1)+j).
// Register budget deliberately ~180 (R4's 290-state spilled to scratch: +60MB traffic).
__global__ __launch_bounds__(512) void odernn_kernel(
    const float* __restrict__ x_seq, const float* __restrict__ t_seq,
    const float* __restrict__ W1,   const float* __restrict__ b1,
    const float* __restrict__ W2,   const float* __restrict__ b2,
    const float* __restrict__ W_ih, const float* __restrict__ W_hh,
    const float* __restrict__ b_ih, const float* __restrict__ b_hh,
    const float* __restrict__ W_mu, const float* __restrict__ b_mu,
    const float* __restrict__ W_lv, const float* __restrict__ b_lv,
    float* __restrict__ out)
{
    __shared__ _Float16 vbuf[16 * 136];                                        // h (fp16)
    __shared__ __attribute__((aligned(16))) unsigned char abuf8[2][16 * 144];  // a_i/A/Abar fp8
    __shared__ _Float16 xbuf[16 * 72];
    __shared__ float    ts_l[Tn];
    __shared__ float    c1s[Hn];          // b2 @ W1^T

    const int tid  = threadIdx.x;
    const int lane = tid & 63;
    const int w    = tid >> 6;
    const int q    = lane >> 4;
    const int m    = lane & 15;
    const int blk  = blockIdx.x;

    if (tid < Tn) ts_l[tid] = t_seq[tid];
    for (int i = tid; i < 16 * 136; i += 512) vbuf[i] = (_Float16)0.f;   // h0 = 0
    if (tid < Hn) {
        float acc = 0.f;
        const float* r1 = W1 + (size_t)tid * Hn;
#pragma unroll 4
        for (int j = 0; j < Hn; j++) acc += b2[j] * r1[j];
        c1s[tid] = acc;
    }

    // ---- fp16 stationary fragments ----
    const int n0 = 16 * w + m;
    half8v w1f[4], whhf[3][4], wihf[3][2];
#pragma unroll
    for (int kt = 0; kt < 4; kt++) w1f[kt] = load_wfrag(W1, Hn, n0, 32 * kt + q * 8);
#pragma unroll
    for (int g = 0; g < 3; g++) {
        int n = 128 * g + n0;
#pragma unroll
        for (int kt = 0; kt < 4; kt++) whhf[g][kt] = load_wfrag(W_hh, Hn, n, 32 * kt + q * 8);
#pragma unroll
        for (int kt = 0; kt < 2; kt++) wihf[g][kt] = load_wfrag(W_ih, Dn, n, 32 * kt + q * 8);
    }
    float4v b1q = *(const float4v*)(b1 + 16 * w + q * 4);
    float4v b2q = *(const float4v*)(b2 + 16 * w + q * 4);
    float4v bihq[3], bhhq[3];
#pragma unroll
    for (int g = 0; g < 3; g++) {
        bihq[g] = *(const float4v*)(b_ih + 128 * g + 16 * w + q * 4);
        bhhq[g] = *(const float4v*)(b_hh + 128 * g + 16 * w + q * 4);
    }

    // ---- M = W1@W2 fragments (one-time VALU dot; natural A-layout k-order) ----
    float4v aM[4][2];
#pragma unroll
    for (int kt = 0; kt < 4; kt++) {
        float4v zz = {0.f, 0.f, 0.f, 0.f};
        aM[kt][0] = zz; aM[kt][1] = zz;
    }
    {
        const float* w1row = W1 + (size_t)n0 * Hn;
        for (int j = 0; j < Hn; j++) {
            float w1v = w1row[j];
            const float* w2r = W2 + (size_t)j * Hn + q * 8;
#pragma unroll
            for (int kt = 0; kt < 4; kt++) {
                aM[kt][0] += w1v * *(const float4v*)(w2r + 32 * kt);
                aM[kt][1] += w1v * *(const float4v*)(w2r + 32 * kt + 4);
            }
        }
    }
    long w21f8[4], w2f8[4];
#pragma unroll
    for (int kt = 0; kt < 4; kt++) {
        w21f8[kt] = pack_fp8x8s(aM[kt][0], aM[kt][1], 64.0f);     // 64*M (avoid fp8 subnormals)
        const float* p = W2 + (size_t)n0 * Hn + 32 * kt + q * 8;
        w2f8[kt] = pack_fp8x8s(*(const float4v*)p, *(const float4v*)(p + 4), 64.0f);
    }

    float4v h = {0.f, 0.f, 0.f, 0.f};

    const int xrow = tid >> 5;
    const int xcol = (tid & 31) * 2;
    const float* xptr = x_seq + (size_t)(blk * 16 + xrow) * (Tn * Dn) + xcol;
    float2v xreg = *(const float2v*)xptr;

    const int wslot = m * 136 + 16 * w + q * 4;   // vbuf C-layout slot
    // fp8 writer position (permuted so reader's contiguous b128s give natural k-order)
    const int ppos = 64 * (w >> 2) + 16 * ((2 * (w & 3) + (q >> 1)) & 3)
                   + 8 * ((w >> 1) & 1) + 4 * (q & 1);
    const float4v zero4 = {0.f, 0.f, 0.f, 0.f};

    auto store_a = [&](int pp, float4v v) {
        *(int*)(abuf8[pp] + m * 144 + ppos) = pack_fp8x4(v[0], v[1], v[2], v[3]);
    };
    // fp8 gemm over K=128: 2x ds_read_b128, 4 MFMAs in 2 chains
    auto gemm8 = [&](const long* Wf, int pp) -> float4v {
        const unsigned char* p = abuf8[pp] + m * 144;
        long2v L0 = *(const long2v*)(p + q * 16);
        long2v L1 = *(const long2v*)(p + 64 + q * 16);
        float4v o1 = zero4, o2 = zero4;
        o1 = __builtin_amdgcn_mfma_f32_16x16x32_fp8_fp8(Wf[0], L0[0], o1, 0, 0, 0);
        o2 = __builtin_amdgcn_mfma_f32_16x16x32_fp8_fp8(Wf[2], L1[0], o2, 0, 0, 0);
        o1 = __builtin_amdgcn_mfma_f32_16x16x32_fp8_fp8(Wf[1], L0[1], o1, 0, 0, 0);
        o2 = __builtin_amdgcn_mfma_f32_16x16x32_fp8_fp8(Wf[3], L1[1], o2, 0, 0, 0);
        return o1 + o2;
    };

    float4v c1q;
    __syncthreads();     // publish ts_l, c1s, vbuf(h0)
#pragma unroll
    for (int r = 0; r < 4; r++) c1q[r] = c1s[16 * w + q * 4 + r];

#pragma unroll 1
    for (int t = 0; t < Tn; ++t) {
        {
            _Float16* xp = xbuf + xrow * 72 + xcol;
            xp[0] = (_Float16)xreg[0]; xp[1] = (_Float16)xreg[1];
        }
        float tc   = ts_l[t];
        float tp   = (t > 0) ? ts_l[t - 1] : tc;
        float sub  = (tc - tp) * 0.25f;
        float hs   = 0.5f * sub;
        float s6   = sub * (1.0f / 6.0f);
        float hs64 = hs * (1.0f / 64.0f);
        float sb64 = sub * (1.0f / 64.0f);
        float s664 = s6 * (1.0f / 64.0f);
        __syncthreads();                  // publish xbuf + vbuf(h)
        if (t + 1 < Tn) xreg = *(const float2v*)(xptr + (t + 1) * Dn);

        // ---- loop-top interval: gi (fp16) + u_h (fp16) ----
        float4v gi[3], u_h;
        {
            const _Float16* xp = xbuf + m * 72 + q * 8;
            half8v xf0 = *(const half8v*)(xp);
            half8v xf1 = *(const half8v*)(xp + 32);
#pragma unroll
            for (int g = 0; g < 3; g++) {
                float4v acc = bihq[g];
                acc = __builtin_amdgcn_mfma_f32_16x16x32_f16(wihf[g][0], xf0, acc, 0, 0, 0);
                acc = __builtin_amdgcn_mfma_f32_16x16x32_f16(wihf[g][1], xf1, acc, 0, 0, 0);
                gi[g] = acc;
            }
            const _Float16* vp = vbuf + m * 136 + q * 8;
            half8v bf0 = *(const half8v*)(vp);
            half8v bf1 = *(const half8v*)(vp + 32);
            half8v bf2 = *(const half8v*)(vp + 64);
            half8v bf3 = *(const half8v*)(vp + 96);
            float4v o1 = b1q, o2 = zero4;
            o1 = __builtin_amdgcn_mfma_f32_16x16x32_f16(w1f[0], bf0, o1, 0, 0, 0);
            o2 = __builtin_amdgcn_mfma_f32_16x16x32_f16(w1f[2], bf2, o2, 0, 0, 0);
            o1 = __builtin_amdgcn_mfma_f32_16x16x32_f16(w1f[1], bf1, o1, 0, 0, 0);
            o2 = __builtin_amdgcn_mfma_f32_16x16x32_f16(w1f[3], bf3, o2, 0, 0, 0);
            u_h = o1 + o2;
        }

        if (sub != 0.0f) {
            float4v Abar = zero4;
#pragma unroll 1
            for (int s = 0; s < 4; s++) {
                float4v a1 = tanh4(u_h);
                float4v A = a1;
                store_a(0, a1);
                __syncthreads();
                float4v g = gemm8(w21f8, 0);
                float4v u = u_h + hs64 * g + hs * c1q;
                float4v a2 = tanh4(u);
                A += 2.0f * a2;
                store_a(1, a2);
                __syncthreads();
                g = gemm8(w21f8, 1);
                u = u_h + hs64 * g + hs * c1q;
                float4v a3 = tanh4(u);
                A += 2.0f * a3;
                store_a(0, a3);
                __syncthreads();
                g = gemm8(w21f8, 0);
                u = u_h + sb64 * g + sub * c1q;
                float4v a4 = tanh4(u);
                A += a4;
                Abar += A;
                if (s < 3) {                       // last substep: u_h is dead, skip
                    store_a(1, A);                 // |A| <= 6
                    __syncthreads();
                    g = gemm8(w21f8, 1);
                    u_h += s664 * g + sub * c1q;
                }
            }
            // ---- Abar exchange -> deferred h update (one fp8 W2-GEMM per step) ----
            store_a(1, Abar);                      // |Abar| <= 24
            __syncthreads();
            float4v gw = gemm8(w2f8, 1);
            h += s664 * gw + (4.0f * sub) * b2q;
            // publish post-RK h
            *(half4v*)(vbuf + wslot) = pack4(h);
            __syncthreads();
        }

        // ---- gh = h Whh^T + bhh (fp16) ----
        float4v gh[3];
        {
            const _Float16* vp = vbuf + m * 136 + q * 8;
            half8v bf0 = *(const half8v*)(vp);
            half8v bf1 = *(const half8v*)(vp + 32);
            half8v bf2 = *(const half8v*)(vp + 64);
            half8v bf3 = *(const half8v*)(vp + 96);
#pragma unroll
            for (int g = 0; g < 3; g++) {
                float4v acc = bhhq[g];
                acc = __builtin_amdgcn_mfma_f32_16x16x32_f16(whhf[g][0], bf0, acc, 0, 0, 0);
                acc = __builtin_amdgcn_mfma_f32_16x16x32_f16(whhf[g][1], bf1, acc, 0, 0, 0);
                acc = __builtin_amdgcn_mfma_f32_16x16x32_f16(whhf[g][2], bf2, acc, 0, 0, 0);
                acc = __builtin_amdgcn_mfma_f32_16x16x32_f16(whhf[g][3], bf3, acc, 0, 0, 0);
                gh[g] = acc;
            }
        }
        __syncthreads();   // all waves done reading vbuf before GRU overwrite

        // ---- GRU (registers) + publish h ----
        {
            half4v pk;
#pragma unroll
            for (int r = 0; r < 4; r++) {
                float rr = fast_sig(gi[0][r] + gh[0][r]);
                float zz = fast_sig(gi[1][r] + gh[1][r]);
                float nn = fast_tanh(gi[2][r] + rr * gh[2][r]);
                float hv = (1.0f - zz) * nn + zz * h[r];
                h[r] = hv;
                pk[r] = (_Float16)hv;
            }
            *(half4v*)(vbuf + wslot) = pk;
        }
        // loop-top barrier publishes vbuf
    }

    __syncthreads();

    // ---- epilogue: mu / logvar (fresh fp16 weight fragments, not persistent) ----
#pragma unroll
    for (int mat = 0; mat < 2; mat++) {
        const float* Wm = mat ? W_lv : W_mu;
        const float* bm = mat ? b_lv : b_mu;
        float4v acc = *(const float4v*)(bm + 16 * w + q * 4);
        const _Float16* p = vbuf + m * 136 + q * 8;
#pragma unroll
        for (int kt = 0; kt < 4; kt++) {
            half8v af = load_wfrag(Wm, Hn, n0, 32 * kt + q * 8);
            acc = __builtin_amdgcn_mfma_f32_16x16x32_f16(af, *(const half8v*)(p + kt * 32), acc, 0, 0, 0);
        }
        *(float4v*)(out + (size_t)mat * Bn * Hn + (size_t)(blk * 16 + m) * Hn + 16 * w + q * 4) = acc;
    }
}

extern "C" void kernel_launch(void* const* d_in, const int* in_sizes, int n_in,
                              void* d_out, int out_size, void* d_ws, size_t ws_size,
                              hipStream_t stream) {
    (void)in_sizes; (void)n_in; (void)d_ws; (void)ws_size; (void)out_size;
    odernn_kernel<<<dim3(Bn / 16), dim3(512), 0, stream>>>(
        (const float*)d_in[0],  (const float*)d_in[1],  (const float*)d_in[2],
        (const float*)d_in[3],  (const float*)d_in[4],  (const float*)d_in[5],
        (const float*)d_in[6],  (const float*)d_in[7],  (const float*)d_in[8],
        (const float*)d_in[9],  (const float*)d_in[10], (const float*)d_in[11],
        (const float*)d_in[12], (const float*)d_in[13], (float*)d_out);
}